// Round 11
// baseline (372.678 us; speedup 1.0000x reference)
//
#include <hip/hip_runtime.h>

// y[n,m,:] = x[n,m,:] @ W[l(m)] * (1/sqrt(128))
// x: [100000, 16, 128] f32   W: [4, 128, 128] f32   y: [100000, 16, 128] f32
//
// R10 post-mortem: granularity neutral (+1%). At 305us NOTHING is saturated
// (HBM 4 TB/s actual vs 6.9 demonstrated, VALU 6%, MFMA 4%, L2 far from
// ceiling) -> residual is serialization, and the only unattacked structure
// is the per-tile barrier convoy (all waves co-arrive behind shared vmcnt).
// R11: BARRIER-FREE wave-private pipeline. Each wave owns a private pair of
// 8KB LDS buffers, stages its own 16-row x-tile (8x global_load_lds), and
// self-syncs with counted vmcnt ONLY -- zero s_barrier. Waves free-run;
// stalls interleave across 8 independent waves/CU. Cost: 4 waves of a block
// fetch the same tile (4x L2 reads ~3.3GB, ~42 B/cy/CU < ~56 L2 ceiling;
// HBM deduped by L2). Buffer reuse guarded per-wave by lgkmcnt(0) +
// sched_barrier(0) (rule 18) before re-staging. Derived per-wave vmcnt
// (8 loads + 2 stores per tile, issue order): NT=8 -> {8,10,12,12,12,12,12,4};
// tail NT=2 -> {8,2}. LDS 64KB -> 2 blocks/CU; ~90 VGPR @ launch_bounds(256,2)
// (cap 256 -- no spill confound).
//
// Unchanged: m-fast grid (R6 page-locality win), gload_lds w=16, rule #21
// both-sides swizzle (source slot^=(row&7), linear DMA dest, XOR on ds_read;
// 2-way bank = free). MFMA: A=W-frag(d), B=x-frag(n), same k->(lanegroup,
// elem) map both sides (K-perm cancels). D: col(lane&15)=n,
// row((lane>>4)*4+reg)=d (HW-verified R1-R10).

typedef __bf16 bf16x8 __attribute__((ext_vector_type(8)));
typedef float f32x4 __attribute__((ext_vector_type(4)));
typedef unsigned short u16x8 __attribute__((ext_vector_type(8)));

#define N_NODES 100000
#define MCOMP 16
#define CIN 128
#define ROWSTRIDE (MCOMP * CIN)  // 2048 floats per node
#define TROWS 16                 // rows per tile (8 KB per wave)

#define VMW(n) asm volatile("s_waitcnt vmcnt(" #n ")" ::: "memory")

__device__ __forceinline__ unsigned short f2b(float f) {
    unsigned int u = __float_as_uint(f);
    unsigned int r = (u + 0x7fffu + ((u >> 16) & 1u)) >> 16;
    return (unsigned short)r;
}

// Wt[l][d][c] = W[l][c][d] * (1/sqrt(128)) as bf16 bits. 128 KiB in d_ws.
__global__ void prep_weights(const float* __restrict__ w,
                             unsigned short* __restrict__ wt) {
    int idx = blockIdx.x * blockDim.x + threadIdx.x;  // 0..65535
    int l = idx >> 14;
    int rem = idx & 16383;
    int d = rem >> 7;
    int c = rem & 127;
    const float pw = 0.08838834764831845f;  // 1/sqrt(128)
    wt[idx] = f2b(w[(l << 14) + (c << 7) + d] * pw);
}

__global__ __launch_bounds__(256, 2) void linear_mfma(
        const float* __restrict__ x,
        const unsigned short* __restrict__ wt,
        float* __restrict__ y) {
    // wave-private: lds[wid][buf] -- no cross-wave LDS access anywhere
    __shared__ float lds[4][2][TROWS * CIN];  // 4 waves x 2 x 8 KiB = 64 KiB

    const int m = blockIdx.x;          // FAST dispatch dim (R6 win)
    const int l = (m >= 9) ? 3 : (m >= 4) ? 2 : (m >= 1) ? 1 : 0;
    const int wid = threadIdx.x >> 6;  // d-slice [wid*32, +32)
    const int lane = threadIdx.x & 63;
    const int lr = lane & 15;   // W-frag d-row / x-frag n(row) / D col
    const int lk = lane >> 4;   // k lane-group
    const int nbase = blockIdx.y * (8 * TROWS);       // 128 rows per block
    const int NT = min(8, (N_NODES - nbase) / TROWS); // 8, or 2 (tail)

    // W fragments, register-resident (32 VGPR):
    // d = wid*32 + df*16 + lr, k = kk*32 + lk*8 .. +8
    const unsigned short* wl = wt + (l << 14);
    bf16x8 wf[2][4];
#pragma unroll
    for (int df = 0; df < 2; ++df)
#pragma unroll
        for (int kk = 0; kk < 4; ++kk)
            wf[df][kk] = __builtin_bit_cast(bf16x8, *(const u16x8*)(
                wl + (((wid * 32 + df * 16 + lr) << 7) + kk * 32 + lk * 8)));

    float* const b0 = &lds[wid][0][0];
    float* const b1 = &lds[wid][1][0];

    // stage tile t (16 rows x 512B) into THIS wave's buf: 8 gload_lds(16B).
    // Instr j covers rows 2j,2j+1: lanes 0-31 -> row 2j, 32-63 -> row 2j+1;
    // LDS dest linear (buf + j*1KB + lane*16B), source slot pre-swizzled.
    auto stage = [&](float* buf, int t) {
        const int hbase = nbase + t * TROWS;
#pragma unroll
        for (int j = 0; j < 8; ++j) {
            int row = 2 * j + (lane >> 5);
            int slot = (lane & 31) ^ (row & 7);  // 16B slot, pre-swizzled
            const float* src = x + (size_t)(hbase + row) * ROWSTRIDE
                               + m * CIN + slot * 4;
            __builtin_amdgcn_global_load_lds(
                (const __attribute__((address_space(1))) void*)src,
                (__attribute__((address_space(3))) void*)(buf + j * 256),
                16, 0, 0);
        }
    };

    // compute tile t from own buf; after draining own ds_reads, re-stage
    // tile t+2 into the SAME buf (no barrier needed: wave-private).
    auto comp = [&](float* buf, int t, bool donext) {
        const int sw = lr & 7;
        const float* rb = buf + lr * CIN;
        f32x4 v[8];
#pragma unroll
        for (int kk = 0; kk < 4; ++kk) {
            v[2 * kk]     = *(const f32x4*)(rb + kk * 32 + ((lk * 2) ^ sw) * 4);
            v[2 * kk + 1] = *(const f32x4*)(rb + kk * 32 + ((lk * 2 + 1) ^ sw) * 4);
        }
        asm volatile("s_waitcnt lgkmcnt(0)" ::: "memory");  // own reads done
        __builtin_amdgcn_sched_barrier(0);                  // rule 18 fence
        if (donext) stage(buf, t + 2);  // overwrite own buf, now safe

        f32x4 acc0 = (f32x4){0.f, 0.f, 0.f, 0.f};
        f32x4 acc1 = (f32x4){0.f, 0.f, 0.f, 0.f};
#pragma unroll
        for (int kk = 0; kk < 4; ++kk) {
            bf16x8 xb;
#pragma unroll
            for (int jj = 0; jj < 4; ++jj) {
                xb[jj]     = (__bf16)v[2 * kk][jj];
                xb[jj + 4] = (__bf16)v[2 * kk + 1][jj];
            }
            acc0 = __builtin_amdgcn_mfma_f32_16x16x32_bf16(wf[0][kk], xb, acc0, 0, 0, 0);
            acc1 = __builtin_amdgcn_mfma_f32_16x16x32_bf16(wf[1][kk], xb, acc1, 0, 0, 0);
        }
        float* yp = y + (size_t)(nbase + t * TROWS + lr) * ROWSTRIDE + m * CIN
                    + wid * 32 + lk * 4;
        *(f32x4*)yp = acc0;        // 2 stores, counted in vmcnt discipline
        *(f32x4*)(yp + 16) = acc1;
    };

    if (NT == 8) {
        stage(b0, 0);
        stage(b1, 1);
        // per-wave derived waits; newer-than-stage(t) = later loads + stores
        VMW(8);  comp(b0, 0, true);   // newer: S1(8)
        VMW(10); comp(b1, 1, true);   // newer: S2(8)+st0(2)
        VMW(12); comp(b0, 2, true);   // newer: st0(2)+S3(8)+st1(2)
        VMW(12); comp(b1, 3, true);
        VMW(12); comp(b0, 4, true);
        VMW(12); comp(b1, 5, true);
        VMW(12); comp(b0, 6, false);  // newer: st4(2)+S7(8)+st5(2)
        VMW(4);  comp(b1, 7, false);  // newer: st5(2)+st6(2)
    } else {
        // tail: 100000 % 128 == 32 -> exactly 2 tiles
        stage(b0, 0);
        stage(b1, 1);
        VMW(8);  comp(b0, 0, false);  // newer: S1(8)
        VMW(2);  comp(b1, 1, false);  // newer: st0(2)
    }
}

extern "C" void kernel_launch(void* const* d_in, const int* in_sizes, int n_in,
                              void* d_out, int out_size, void* d_ws, size_t ws_size,
                              hipStream_t stream) {
    const float* x = (const float*)d_in[0];
    const float* w = (const float*)d_in[1];
    float* y = (float*)d_out;
    unsigned short* wt = (unsigned short*)d_ws;  // 128 KiB of scratch used

    prep_weights<<<256, 256, 0, stream>>>(w, wt);

    // m fast, node-tile slow (R6 win): one sequential HBM sweep.
    dim3 grid(MCOMP, (N_NODES + 127) / 128);  // 16 x 782
    linear_mfma<<<grid, 256, 0, stream>>>(x, wt, y);
}